// Round 5
// baseline (135.248 us; speedup 1.0000x reference)
//
#include <hip/hip_runtime.h>
#include <hip/hip_bf16.h>

#define NN 9216
#define CC 256
#define LOG2E 1.4426950408889634f

typedef __attribute__((ext_vector_type(8))) short short8;
typedef __attribute__((ext_vector_type(16))) float floatx16;
typedef __attribute__((ext_vector_type(4))) float floatx4;
typedef __attribute__((ext_vector_type(4))) unsigned short ushortx4;

#if __has_builtin(__builtin_amdgcn_exp2f)
#define fexp2 __builtin_amdgcn_exp2f
#else
#define fexp2 exp2f
#endif

__device__ __forceinline__ unsigned short f2bf(float f) {
    unsigned u = __float_as_uint(f);
    u = u + 0x7fffu + ((u >> 16) & 1u);
    return (unsigned short)(u >> 16);
}
__device__ __forceinline__ float bf2f(unsigned short s) {
    return __uint_as_float(((unsigned)s) << 16);
}
__device__ __forceinline__ unsigned pack2bf(float a, float b) {
    union { __hip_bfloat162 h; unsigned u; } cv;
    cv.h = __float22bfloat162_rn(make_float2(a, b));
    return cv.u;
}
__device__ __forceinline__ floatx16 mfma_bf16(short8 a, short8 b, floatx16 c) {
    return __builtin_amdgcn_mfma_f32_32x32x16_bf16(a, b, c, 0, 0, 0);
}

// K0: transpose+hi/lo-split inputs into B-fragment order XB/EB[nt][kb][lane][8].
__global__ __launch_bounds__(256) void prep(
    const float* __restrict__ x, const float* __restrict__ xe,
    short* __restrict__ XBhi, short* __restrict__ XBlo,
    short* __restrict__ EBhi, short* __restrict__ EBlo)
{
    int t = threadIdx.x;
    const float* in = blockIdx.y ? xe : x;
    short* Dhi = blockIdx.y ? EBhi : XBhi;
    short* Dlo = blockIdx.y ? EBlo : XBlo;
    int tl = t & 31, sub = t >> 5;
    int nt = blockIdx.x >> 2, q4 = blockIdx.x & 3;
    int sub2 = q4 * 8 + sub;            // 0..31
    int kb_ = sub2 >> 1, hl = sub2 & 1;
    int n = nt * 32 + tl;
    int c0 = kb_ * 16 + hl * 8;
    union { unsigned short us[8]; short8 v8; } hi, lo;
#pragma unroll
    for (int j = 0; j < 8; ++j) {
        float val = in[(size_t)(c0 + j) * NN + n];
        unsigned short hb = f2bf(val);
        hi.us[j] = hb;
        lo.us[j] = f2bf(val - bf2f(hb));
    }
    size_t off = (((size_t)nt * 16 + kb_) * 64 + hl * 32 + tl) * 8;
    *(short8*)(Dhi + off) = hi.v8;
    *(short8*)(Dlo + off) = lo.v8;
}

// K0b: weights -> A-fragment order WA[ot][kb][lane][8], hi/lo split.
__global__ __launch_bounds__(256) void wprep(
    const float* __restrict__ qw, const float* __restrict__ kw,
    const float* __restrict__ vw,
    short* __restrict__ WAhi, short* __restrict__ WAlo)
{
    int g = blockIdx.x * 256 + threadIdx.x;     // 0..10239
    int lane = g & 63, kb_ = (g >> 6) & 15, ot = g >> 10;
    int o = lane & 31, half = lane >> 5;
    int c0 = kb_ * 16 + half * 8;
    const float* wsrc;
    int orow;
    float scale = 1.f;
    if (ot == 0) { wsrc = qw; orow = o; scale = LOG2E; }
    else if (ot == 1) { wsrc = kw; orow = o; }
    else { wsrc = vw; orow = (ot - 2) * 32 + o; }
    union { unsigned short us[8]; short8 v8; } hi, lo;
#pragma unroll
    for (int j = 0; j < 8; ++j) {
        float val = wsrc[(size_t)orow * 256 + c0 + j] * scale;
        unsigned short hb = f2bf(val);
        hi.us[j] = hb;
        lo.us[j] = f2bf(val - bf2f(hb));
    }
    size_t off = (((size_t)ot * 16 + kb_) * 64 + lane) * 8;
    *(short8*)(WAhi + off) = hi.v8;
    *(short8*)(WAlo + off) = lo.v8;
}

// K1: all projections via MFMA (see round-2 notes). grid (144, 5), 256 thr.
__global__ __launch_bounds__(256) void gemm_all(
    const short* __restrict__ XBhi, const short* __restrict__ XBlo,
    const short* __restrict__ EBhi, const short* __restrict__ EBlo,
    const short* __restrict__ WAhi, const short* __restrict__ WAlo,
    const float* __restrict__ qb, const float* __restrict__ kb,
    const float* __restrict__ hpos, const float* __restrict__ wpos,
    const float* __restrict__ vb,
    short* __restrict__ Qhi, short* __restrict__ Qlo,
    short* __restrict__ KP2, short* __restrict__ VF)
{
    __shared__ float lds[4][1024];
    int t = threadIdx.x;
    int wv = t >> 6, lane = t & 63, ln = lane & 31, h = lane >> 5;
    int nt = blockIdx.x * 2 + (wv & 1);
    int tile = blockIdx.y * 2 + (wv >> 1);

    const short* Bhi = (tile == 0 ? XBhi : EBhi) + (size_t)nt * 8192 + lane * 8;
    const short* Blo = (tile == 0 ? XBlo : EBlo) + (size_t)nt * 8192 + lane * 8;
    const short* Ahi = WAhi + (size_t)tile * 8192 + lane * 8;
    const short* Alo = WAlo + (size_t)tile * 8192 + lane * 8;

    floatx16 D;
#pragma unroll
    for (int r = 0; r < 16; ++r) D[r] = 0.f;
#pragma unroll
    for (int k = 0; k < 16; ++k) {
        short8 bh = *(const short8*)(Bhi + k * 512);
        short8 bl = *(const short8*)(Blo + k * 512);
        short8 ah = *(const short8*)(Ahi + k * 512);
        short8 al = *(const short8*)(Alo + k * 512);
        D = mfma_bf16(ah, bh, D);
        D = mfma_bf16(ah, bl, D);
        D = mfma_bf16(al, bh, D);
    }

    float* L = lds[wv];
#pragma unroll
    for (int r = 0; r < 16; ++r) {
        int row = (r & 3) + 8 * (r >> 2) + 4 * h;
        L[row * 32 + ((ln + row) & 31)] = D[r];     // (col+row)&31 bank swizzle
    }
    __syncthreads();

    if (tile == 0) {
        int n = nt * 32 + ln;
#pragma unroll
        for (int it = 0; it < 2; ++it) {
            int j0 = it * 16 + h * 8;
            union { unsigned short us[8]; short8 v8; } qh_, ql_;
#pragma unroll
            for (int jj = 0; jj < 8; ++jj) {
                int row = j0 + jj;
                float d = L[row * 32 + ((ln + row) & 31)] + qb[row] * LOG2E;
                unsigned short hb = f2bf(d);
                qh_.us[jj] = hb;
                ql_.us[jj] = f2bf(d - bf2f(hb));
            }
            *(short8*)(Qhi + (size_t)n * 32 + j0) = qh_.v8;
            *(short8*)(Qlo + (size_t)n * 32 + j0) = ql_.v8;
        }
    } else if (tile == 1) {
        int n = nt * 32 + ln;
        int hh = ((n >> 5) * 683) >> 11;     // n/96
        int ww = n - hh * 96;
#pragma unroll
        for (int it = 0; it < 2; ++it) {
            int jb0 = it * 16 + h * 8;
            union { unsigned short us[8]; short8 v8; } o;
#pragma unroll
            for (int jj = 0; jj < 8; ++jj) {
                int row = jb0 + jj;
                float d = L[row * 32 + ((ln + row) & 31)]
                        + kb[row] + hpos[row * 96 + hh] + wpos[row * 96 + ww];
                o.us[jj] = f2bf(d);
            }
            *(short8*)(KP2 + (size_t)nt * 1024 + it * 512 + h * 256 + ln * 8) = o.v8;
        }
    } else {
        int cc = tile - 2;
        float bias = vb[cc * 32 + ln];
#pragma unroll
        for (int it = 0; it < 2; ++it) {
            union { unsigned short us[8]; short8 v8; } o;
#pragma unroll
            for (int ee = 0; ee < 8; ++ee) {
                int ml = it * 16 + h * 8 + ee;
                float d = L[ln * 32 + ((ml + ln) & 31)];
                o.us[ee] = f2bf(d + bias);
            }
            *(short8*)(VF + ((size_t)(nt * 2 + it) * 8 + cc) * 512 + lane * 8) = o.v8;
        }
    }
}

// K3: flash attention. Wave = 64 n x 128 c: each V fragment (held in regs) feeds
// TWO PV MFMAs (n-tiles A,B) -> V L1 traffic per output halves vs 32n waves.
// Block = 2 waves with IDENTICAL V/KP addresses (same mq, same c-half, adjacent
// 64n tiles) -> in-block L1 hit sharing. grid = 72 ntp * 4 mq * 2 ch = 576,
// 128 thr. Fixed-max softmax (max=0), parts=4 (Opart/stats/combine unchanged).
#define SMPV(S, V0, V1, V2, V3, U0, U1, U2, U3, OA, OB, OC, OD, LACC) do {            \
    float ps = 0.f;                                                                   \
    _Pragma("unroll") for (int r = 0; r < 16; ++r) { S[r] = fexp2(S[r]); ps += S[r]; } \
    ps += __shfl_xor(ps, 32); LACC += ps;                                             \
    unsigned w0 = pack2bf(S[0], S[1]),  w1 = pack2bf(S[2], S[3]);                     \
    unsigned w2 = pack2bf(S[4], S[5]),  w3 = pack2bf(S[6], S[7]);                     \
    unsigned w4 = pack2bf(S[8], S[9]),  w5 = pack2bf(S[10], S[11]);                   \
    unsigned w6 = pack2bf(S[12], S[13]), w7 = pack2bf(S[14], S[15]);                  \
    {   unsigned p0 = h ? w0 : w2, p1 = h ? w1 : w3;                                  \
        unsigned e0 = (unsigned)__shfl_xor((int)p0, 32);                              \
        unsigned e1 = (unsigned)__shfl_xor((int)p1, 32);                              \
        union { unsigned u[4]; short8 v; } pf;                                        \
        pf.u[0] = h ? e0 : w0; pf.u[1] = h ? e1 : w1;                                 \
        pf.u[2] = h ? w2 : e0; pf.u[3] = h ? w3 : e1;                                 \
        OA = mfma_bf16(V0, pf.v, OA); OB = mfma_bf16(V1, pf.v, OB);                   \
        OC = mfma_bf16(V2, pf.v, OC); OD = mfma_bf16(V3, pf.v, OD); }                 \
    {   unsigned p0 = h ? w4 : w6, p1 = h ? w5 : w7;                                  \
        unsigned e0 = (unsigned)__shfl_xor((int)p0, 32);                              \
        unsigned e1 = (unsigned)__shfl_xor((int)p1, 32);                              \
        union { unsigned u[4]; short8 v; } pf;                                        \
        pf.u[0] = h ? e0 : w4; pf.u[1] = h ? e1 : w5;                                 \
        pf.u[2] = h ? w6 : e0; pf.u[3] = h ? w7 : e1;                                 \
        OA = mfma_bf16(U0, pf.v, OA); OB = mfma_bf16(U1, pf.v, OB);                   \
        OC = mfma_bf16(U2, pf.v, OC); OD = mfma_bf16(U3, pf.v, OD); }                 \
} while (0)

#define OGW2(CF, T, OG) { _Pragma("unroll") for (int r = 0; r < 16; ++r) {            \
    int row = ch * 128 + (CF) * 32 + (r & 3) + 8 * (r >> 2) + 4 * h;                  \
    Opart[obase + (size_t)row * NN + n0 + (T) * 32 + ln] = f2bf(OG[r]); } }

__global__ __launch_bounds__(128, 2) void flash(
    const short* __restrict__ Qhi, const short* __restrict__ Qlo,
    const short* __restrict__ KP2, const short* __restrict__ VF,
    unsigned short* __restrict__ Opart, float* __restrict__ Lpart)
{
    int t = threadIdx.x;
    int wv = t >> 6;                    // n-64 subtile within block
    int lane = t & 63;
    int ln = lane & 31;
    int h = lane >> 5;
    int bx = blockIdx.x;
    int ntp = bx >> 3, mq = (bx >> 1) & 3, ch = bx & 1;
    int n0 = ntp * 128 + wv * 64;
    int mstart = mq * 2304;

    // Q fragments for the wave's two n-tiles (A: n0.., B: n0+32..)
    int qoffA = (n0 + ln) * 32 + h * 8;
    int qoffB = (n0 + 32 + ln) * 32 + h * 8;
    short8 qAh0 = *(const short8*)(Qhi + qoffA);
    short8 qAl0 = *(const short8*)(Qlo + qoffA);
    short8 qAh1 = *(const short8*)(Qhi + qoffA + 16);
    short8 qAl1 = *(const short8*)(Qlo + qoffA + 16);
    short8 qBh0 = *(const short8*)(Qhi + qoffB);
    short8 qBl0 = *(const short8*)(Qlo + qoffB);
    short8 qBh1 = *(const short8*)(Qhi + qoffB + 16);
    short8 qBl1 = *(const short8*)(Qlo + qoffB + 16);

    // Per-c-half V base: VF[mc][cc][lane][8]; cc = ch*4 + cf.
    const short* Vb  = VF + (size_t)(mstart >> 4) * 4096 + ch * 2048 + lane * 8;
    const short* KPb = KP2 + (size_t)mstart * 32 + lane * 8;

    floatx16 O00, O10, O20, O30, O01, O11, O21, O31;
#pragma unroll
    for (int r = 0; r < 16; ++r) {
        O00[r] = 0.f; O10[r] = 0.f; O20[r] = 0.f; O30[r] = 0.f;
        O01[r] = 0.f; O11[r] = 0.f; O21[r] = 0.f; O31[r] = 0.f;
    }
    float l0 = 0.f, l1 = 0.f;

    short8 ah0 = *(const short8*)(KPb);
    short8 ah1 = *(const short8*)(KPb + 512);

    for (int sp = 0; sp < 72; ++sp) {
        const short* Vp = Vb + (size_t)sp * 8192;
        short8 vf00 = *(const short8*)(Vp);
        short8 vf10 = *(const short8*)(Vp + 512);
        short8 vf20 = *(const short8*)(Vp + 1024);
        short8 vf30 = *(const short8*)(Vp + 1536);
        short8 vf01 = *(const short8*)(Vp + 4096);
        short8 vf11 = *(const short8*)(Vp + 4608);
        short8 vf21 = *(const short8*)(Vp + 5120);
        short8 vf31 = *(const short8*)(Vp + 5632);

        int nm = (sp < 71) ? sp + 1 : 0;
        short8 an0 = *(const short8*)(KPb + (size_t)nm * 1024);
        short8 an1 = *(const short8*)(KPb + (size_t)nm * 1024 + 512);

        floatx16 SA = {0.f,0.f,0.f,0.f,0.f,0.f,0.f,0.f,0.f,0.f,0.f,0.f,0.f,0.f,0.f,0.f};
        SA = mfma_bf16(ah0, qAh0, SA);
        SA = mfma_bf16(ah0, qAl0, SA);
        SA = mfma_bf16(ah1, qAh1, SA);
        SA = mfma_bf16(ah1, qAl1, SA);
        SMPV(SA, vf00, vf10, vf20, vf30, vf01, vf11, vf21, vf31,
             O00, O10, O20, O30, l0);

        floatx16 SB = {0.f,0.f,0.f,0.f,0.f,0.f,0.f,0.f,0.f,0.f,0.f,0.f,0.f,0.f,0.f,0.f};
        SB = mfma_bf16(ah0, qBh0, SB);
        SB = mfma_bf16(ah0, qBl0, SB);
        SB = mfma_bf16(ah1, qBh1, SB);
        SB = mfma_bf16(ah1, qBl1, SB);
        SMPV(SB, vf00, vf10, vf20, vf30, vf01, vf11, vf21, vf31,
             O01, O11, O21, O31, l1);

        ah0 = an0; ah1 = an1;
    }

    if (ch == 0 && lane < 32) {
        Lpart[mq * NN + n0 + ln] = l0;
        Lpart[mq * NN + n0 + 32 + ln] = l1;
    }
    size_t obase = (size_t)mq * ((size_t)CC * NN);
    OGW2(0, 0, O00) OGW2(1, 0, O10) OGW2(2, 0, O20) OGW2(3, 0, O30)
    OGW2(0, 1, O01) OGW2(1, 1, O11) OGW2(2, 1, O21) OGW2(3, 1, O31)
}

// K4: fixed-max parts => single weight W[n] = gamma / sum_q L_q[n]. grid 36x256.
__global__ __launch_bounds__(256) void stats(
    const float* __restrict__ Lpart, const float* __restrict__ gamma,
    float* __restrict__ W)
{
    int n = blockIdx.x * 256 + threadIdx.x;
    float L = Lpart[n] + Lpart[NN + n] + Lpart[2 * NN + n] + Lpart[3 * NN + n];
    W[n] = gamma[0] / L;
}

// K5: out[c][n] = (sum_q Opart_q[c][n]) * W[n] + x[c][n]
__global__ __launch_bounds__(256) void combine(
    const unsigned short* __restrict__ Opart, const float* __restrict__ W,
    const float* __restrict__ x, float* __restrict__ out)
{
    int i = blockIdx.x * 256 + threadIdx.x;   // float4 index
    int flat = i * 4;
    int n = flat % NN;                        // 4-aligned, NN%4==0 so no row cross
    floatx4 acc = *(const floatx4*)&x[flat];
    floatx4 w = *(const floatx4*)&W[n];
    float s0 = 0.f, s1 = 0.f, s2 = 0.f, s3 = 0.f;
#pragma unroll
    for (int q = 0; q < 4; ++q) {
        ushortx4 o = *(const ushortx4*)(Opart + (size_t)q * ((size_t)CC * NN) + flat);
        s0 += bf2f(o[0]); s1 += bf2f(o[1]); s2 += bf2f(o[2]); s3 += bf2f(o[3]);
    }
    acc[0] += s0 * w[0]; acc[1] += s1 * w[1]; acc[2] += s2 * w[2]; acc[3] += s3 * w[3];
    *(floatx4*)&out[flat] = acc;
}

extern "C" void kernel_launch(void* const* d_in, const int* in_sizes, int n_in,
                              void* d_out, int out_size, void* d_ws, size_t ws_size,
                              hipStream_t stream) {
    const float* x  = (const float*)d_in[0];
    const float* xe = (const float*)d_in[1];
    const float* qw = (const float*)d_in[2];
    const float* qb = (const float*)d_in[3];
    const float* kw = (const float*)d_in[4];
    const float* kb = (const float*)d_in[5];
    const float* vw = (const float*)d_in[6];
    const float* vb = (const float*)d_in[7];
    const float* hp = (const float*)d_in[8];
    const float* wp = (const float*)d_in[9];
    const float* gm = (const float*)d_in[10];

    char* ws = (char*)d_ws;
    short* Qhi  = (short*)(ws + 0);                 // 589824 B
    short* Qlo  = (short*)(ws + 589824);            // 589824 B
    short* KP2  = (short*)(ws + 1179648);           // 589824 B
    short* WAhi = (short*)(ws + 1769472);           // 163840 B
    short* WAlo = (short*)(ws + 1933312);           // 163840 B
    short* VF   = (short*)(ws + 2097152);           // 4718592 B, ends 6815744
    unsigned short* Opart = (unsigned short*)(ws + 6815744);   // 18874368 B, ends 25690112
    // XB/EB staging overlays Opart (consumed by gemm_all before flash writes Opart)
    short* XBhi = (short*)(ws + 6815744);           // 4718592 B each
    short* XBlo = (short*)(ws + 11534336);
    short* EBhi = (short*)(ws + 16252928);
    short* EBlo = (short*)(ws + 20971520);
    float* Lpart = (float*)(ws + 25837568);         // 147456 B
    float* W     = (float*)(ws + 25985024);         // 36864 B used

    prep<<<dim3(1152, 2), dim3(256), 0, stream>>>(x, xe, XBhi, XBlo, EBhi, EBlo);
    wprep<<<dim3(40), dim3(256), 0, stream>>>(qw, kw, vw, WAhi, WAlo);
    gemm_all<<<dim3(144, 5), dim3(256), 0, stream>>>(
        XBhi, XBlo, EBhi, EBlo, WAhi, WAlo, qb, kb, hp, wp, vb, Qhi, Qlo, KP2, VF);
    flash<<<dim3(576), dim3(128), 0, stream>>>(Qhi, Qlo, KP2, VF, Opart, Lpart);
    stats<<<dim3(36), dim3(256), 0, stream>>>(Lpart, gm, W);
    combine<<<dim3(2304), dim3(256), 0, stream>>>(Opart, W, x, (float*)d_out);
}

// Round 6
// 129.406 us; speedup vs baseline: 1.0451x; 1.0451x over previous
//
#include <hip/hip_runtime.h>
#include <hip/hip_bf16.h>

#define NN 9216
#define CC 256
#define LOG2E 1.4426950408889634f

typedef __attribute__((ext_vector_type(8))) short short8;
typedef __attribute__((ext_vector_type(16))) float floatx16;
typedef __attribute__((ext_vector_type(4))) float floatx4;
typedef __attribute__((ext_vector_type(4))) unsigned short ushortx4;

#if __has_builtin(__builtin_amdgcn_exp2f)
#define fexp2 __builtin_amdgcn_exp2f
#else
#define fexp2 exp2f
#endif

__device__ __forceinline__ unsigned short f2bf(float f) {
    unsigned u = __float_as_uint(f);
    u = u + 0x7fffu + ((u >> 16) & 1u);
    return (unsigned short)(u >> 16);
}
__device__ __forceinline__ float bf2f(unsigned short s) {
    return __uint_as_float(((unsigned)s) << 16);
}
__device__ __forceinline__ unsigned pack2bf(float a, float b) {
    union { __hip_bfloat162 h; unsigned u; } cv;
    cv.h = __float22bfloat162_rn(make_float2(a, b));
    return cv.u;
}
__device__ __forceinline__ floatx16 mfma_bf16(short8 a, short8 b, floatx16 c) {
    return __builtin_amdgcn_mfma_f32_32x32x16_bf16(a, b, c, 0, 0, 0);
}

// K0: transpose+hi/lo-split inputs into B-fragment order XB/EB[nt][kb][lane][8].
__global__ __launch_bounds__(256) void prep(
    const float* __restrict__ x, const float* __restrict__ xe,
    short* __restrict__ XBhi, short* __restrict__ XBlo,
    short* __restrict__ EBhi, short* __restrict__ EBlo)
{
    int t = threadIdx.x;
    const float* in = blockIdx.y ? xe : x;
    short* Dhi = blockIdx.y ? EBhi : XBhi;
    short* Dlo = blockIdx.y ? EBlo : XBlo;
    int tl = t & 31, sub = t >> 5;
    int nt = blockIdx.x >> 2, q4 = blockIdx.x & 3;
    int sub2 = q4 * 8 + sub;            // 0..31
    int kb_ = sub2 >> 1, hl = sub2 & 1;
    int n = nt * 32 + tl;
    int c0 = kb_ * 16 + hl * 8;
    union { unsigned short us[8]; short8 v8; } hi, lo;
#pragma unroll
    for (int j = 0; j < 8; ++j) {
        float val = in[(size_t)(c0 + j) * NN + n];
        unsigned short hb = f2bf(val);
        hi.us[j] = hb;
        lo.us[j] = f2bf(val - bf2f(hb));
    }
    size_t off = (((size_t)nt * 16 + kb_) * 64 + hl * 32 + tl) * 8;
    *(short8*)(Dhi + off) = hi.v8;
    *(short8*)(Dlo + off) = lo.v8;
}

// K0b: weights -> A-fragment order WA[ot][kb][lane][8], hi/lo split.
__global__ __launch_bounds__(256) void wprep(
    const float* __restrict__ qw, const float* __restrict__ kw,
    const float* __restrict__ vw,
    short* __restrict__ WAhi, short* __restrict__ WAlo)
{
    int g = blockIdx.x * 256 + threadIdx.x;     // 0..10239
    int lane = g & 63, kb_ = (g >> 6) & 15, ot = g >> 10;
    int o = lane & 31, half = lane >> 5;
    int c0 = kb_ * 16 + half * 8;
    const float* wsrc;
    int orow;
    float scale = 1.f;
    if (ot == 0) { wsrc = qw; orow = o; scale = LOG2E; }
    else if (ot == 1) { wsrc = kw; orow = o; }
    else { wsrc = vw; orow = (ot - 2) * 32 + o; }
    union { unsigned short us[8]; short8 v8; } hi, lo;
#pragma unroll
    for (int j = 0; j < 8; ++j) {
        float val = wsrc[(size_t)orow * 256 + c0 + j] * scale;
        unsigned short hb = f2bf(val);
        hi.us[j] = hb;
        lo.us[j] = f2bf(val - bf2f(hb));
    }
    size_t off = (((size_t)ot * 16 + kb_) * 64 + lane) * 8;
    *(short8*)(WAhi + off) = hi.v8;
    *(short8*)(WAlo + off) = lo.v8;
}

// K1: all projections via MFMA (see round-2 notes). grid (144, 5), 256 thr.
__global__ __launch_bounds__(256) void gemm_all(
    const short* __restrict__ XBhi, const short* __restrict__ XBlo,
    const short* __restrict__ EBhi, const short* __restrict__ EBlo,
    const short* __restrict__ WAhi, const short* __restrict__ WAlo,
    const float* __restrict__ qb, const float* __restrict__ kb,
    const float* __restrict__ hpos, const float* __restrict__ wpos,
    const float* __restrict__ vb,
    short* __restrict__ Qhi, short* __restrict__ Qlo,
    short* __restrict__ KP2, short* __restrict__ VF)
{
    __shared__ float lds[4][1024];
    int t = threadIdx.x;
    int wv = t >> 6, lane = t & 63, ln = lane & 31, h = lane >> 5;
    int nt = blockIdx.x * 2 + (wv & 1);
    int tile = blockIdx.y * 2 + (wv >> 1);

    const short* Bhi = (tile == 0 ? XBhi : EBhi) + (size_t)nt * 8192 + lane * 8;
    const short* Blo = (tile == 0 ? XBlo : EBlo) + (size_t)nt * 8192 + lane * 8;
    const short* Ahi = WAhi + (size_t)tile * 8192 + lane * 8;
    const short* Alo = WAlo + (size_t)tile * 8192 + lane * 8;

    floatx16 D;
#pragma unroll
    for (int r = 0; r < 16; ++r) D[r] = 0.f;
#pragma unroll
    for (int k = 0; k < 16; ++k) {
        short8 bh = *(const short8*)(Bhi + k * 512);
        short8 bl = *(const short8*)(Blo + k * 512);
        short8 ah = *(const short8*)(Ahi + k * 512);
        short8 al = *(const short8*)(Alo + k * 512);
        D = mfma_bf16(ah, bh, D);
        D = mfma_bf16(ah, bl, D);
        D = mfma_bf16(al, bh, D);
    }

    float* L = lds[wv];
#pragma unroll
    for (int r = 0; r < 16; ++r) {
        int row = (r & 3) + 8 * (r >> 2) + 4 * h;
        L[row * 32 + ((ln + row) & 31)] = D[r];     // (col+row)&31 bank swizzle
    }
    __syncthreads();

    if (tile == 0) {
        int n = nt * 32 + ln;
#pragma unroll
        for (int it = 0; it < 2; ++it) {
            int j0 = it * 16 + h * 8;
            union { unsigned short us[8]; short8 v8; } qh_, ql_;
#pragma unroll
            for (int jj = 0; jj < 8; ++jj) {
                int row = j0 + jj;
                float d = L[row * 32 + ((ln + row) & 31)] + qb[row] * LOG2E;
                unsigned short hb = f2bf(d);
                qh_.us[jj] = hb;
                ql_.us[jj] = f2bf(d - bf2f(hb));
            }
            *(short8*)(Qhi + (size_t)n * 32 + j0) = qh_.v8;
            *(short8*)(Qlo + (size_t)n * 32 + j0) = ql_.v8;
        }
    } else if (tile == 1) {
        int n = nt * 32 + ln;
        int hh = ((n >> 5) * 683) >> 11;     // n/96
        int ww = n - hh * 96;
#pragma unroll
        for (int it = 0; it < 2; ++it) {
            int jb0 = it * 16 + h * 8;
            union { unsigned short us[8]; short8 v8; } o;
#pragma unroll
            for (int jj = 0; jj < 8; ++jj) {
                int row = jb0 + jj;
                float d = L[row * 32 + ((ln + row) & 31)]
                        + kb[row] + hpos[row * 96 + hh] + wpos[row * 96 + ww];
                o.us[jj] = f2bf(d);
            }
            *(short8*)(KP2 + (size_t)nt * 1024 + it * 512 + h * 256 + ln * 8) = o.v8;
        }
    } else {
        int cc = tile - 2;
        float bias = vb[cc * 32 + ln];
#pragma unroll
        for (int it = 0; it < 2; ++it) {
            union { unsigned short us[8]; short8 v8; } o;
#pragma unroll
            for (int ee = 0; ee < 8; ++ee) {
                int ml = it * 16 + h * 8 + ee;
                float d = L[ln * 32 + ((ml + ln) & 31)];
                o.us[ee] = f2bf(d + bias);
            }
            *(short8*)(VF + ((size_t)(nt * 2 + it) * 8 + cc) * 512 + lane * 8) = o.v8;
        }
    }
}

// K3: flash attention. Wave = 32 n x 128 c (O = 4 x floatx16 = 64 acc -> ~half the
// register footprint of the 256c wave => 2 waves/SIMD resident instead of ~1).
// Block = 128 thr = 2 waves with IDENTICAL V/KP addresses (adjacent 32n tiles,
// same mq & c-half) -> L1 hit sharing. grid = 144 ntp * 4 mq * 2 ch = 1152 blocks
// = 2304 waves (~2/SIMD, 4.5 blocks/CU -> fine-grained tail). QK^T and softmax are
// x2 redundant across c-halves (cheap: ~+4us MFMA, +2us VALU chip-wide).
// Fixed-max softmax (max=0): energies ~N(0,sigma~10) in log2 domain, far from f32
// range limits, so exp2(S) direct is exact softmax. Parts=4 unchanged downstream.
#define OGW(CF, OG) { _Pragma("unroll") for (int r = 0; r < 16; ++r) {                \
    int row = ch * 128 + (CF) * 32 + (r & 3) + 8 * (r >> 2) + 4 * h;                  \
    Opart[obase + (size_t)row * NN + n0 + ln] = f2bf(OG[r]); } }

__global__ __launch_bounds__(128, 2) void flash(
    const short* __restrict__ Qhi, const short* __restrict__ Qlo,
    const short* __restrict__ KP2, const short* __restrict__ VF,
    unsigned short* __restrict__ Opart, float* __restrict__ Lpart)
{
    int t = threadIdx.x;
    int wv = t >> 6;                    // n-subtile within block
    int lane = t & 63;
    int ln = lane & 31;
    int h = lane >> 5;
    int bx = blockIdx.x;
    int ntp = bx >> 3, mq = (bx >> 1) & 3, ch = bx & 1;
    int n0 = ntp * 64 + wv * 32;
    int mstart = mq * 2304;

    int qoff = (n0 + ln) * 32 + h * 8;
    short8 qf00 = *(const short8*)(Qhi + qoff);
    short8 qf01 = *(const short8*)(Qlo + qoff);
    short8 qf10 = *(const short8*)(Qhi + qoff + 16);
    short8 qf11 = *(const short8*)(Qlo + qoff + 16);

    // V base for this c-half: VF[mc][cc][lane][8], cc = ch*4 + cf.
    const short* Vb  = VF + (size_t)(mstart >> 4) * 4096 + ch * 2048 + lane * 8;
    const short* KPb = KP2 + (size_t)mstart * 32 + lane * 8;

    floatx16 O0, O1, O2, O3;            // c-tiles ch*128 + {0,32,64,96}
#pragma unroll
    for (int r = 0; r < 16; ++r) { O0[r] = 0.f; O1[r] = 0.f; O2[r] = 0.f; O3[r] = 0.f; }
    float l_run = 0.f;

    short8 ah0 = *(const short8*)(KPb);
    short8 ah1 = *(const short8*)(KPb + 512);

    for (int sp = 0; sp < 72; ++sp) {
        const short* Vp = Vb + (size_t)sp * 8192;
        short8 va0 = *(const short8*)(Vp);
        short8 va1 = *(const short8*)(Vp + 512);
        short8 va2 = *(const short8*)(Vp + 1024);
        short8 va3 = *(const short8*)(Vp + 1536);
        short8 vb0 = *(const short8*)(Vp + 4096);
        short8 vb1 = *(const short8*)(Vp + 4608);
        short8 vb2 = *(const short8*)(Vp + 5120);
        short8 vb3 = *(const short8*)(Vp + 5632);

        int nm = (sp < 71) ? sp + 1 : 0;
        short8 an0 = *(const short8*)(KPb + (size_t)nm * 1024);
        short8 an1 = *(const short8*)(KPb + (size_t)nm * 1024 + 512);

        floatx16 S = {0.f,0.f,0.f,0.f,0.f,0.f,0.f,0.f,0.f,0.f,0.f,0.f,0.f,0.f,0.f,0.f};
        S = mfma_bf16(ah0, qf00, S);
        S = mfma_bf16(ah0, qf01, S);
        S = mfma_bf16(ah1, qf10, S);
        S = mfma_bf16(ah1, qf11, S);

        float ps = 0.f;
#pragma unroll
        for (int r = 0; r < 16; ++r) { S[r] = fexp2(S[r]); ps += S[r]; }
        ps += __shfl_xor(ps, 32); l_run += ps;

        unsigned w0 = pack2bf(S[0], S[1]),  w1 = pack2bf(S[2], S[3]);
        unsigned w2 = pack2bf(S[4], S[5]),  w3 = pack2bf(S[6], S[7]);
        unsigned w4 = pack2bf(S[8], S[9]),  w5 = pack2bf(S[10], S[11]);
        unsigned w6 = pack2bf(S[12], S[13]), w7 = pack2bf(S[14], S[15]);
        {   unsigned p0 = h ? w0 : w2, p1 = h ? w1 : w3;
            unsigned e0 = (unsigned)__shfl_xor((int)p0, 32);
            unsigned e1 = (unsigned)__shfl_xor((int)p1, 32);
            union { unsigned u[4]; short8 v; } pf;
            pf.u[0] = h ? e0 : w0; pf.u[1] = h ? e1 : w1;
            pf.u[2] = h ? w2 : e0; pf.u[3] = h ? w3 : e1;
            O0 = mfma_bf16(va0, pf.v, O0); O1 = mfma_bf16(va1, pf.v, O1);
            O2 = mfma_bf16(va2, pf.v, O2); O3 = mfma_bf16(va3, pf.v, O3);
        }
        {   unsigned p0 = h ? w4 : w6, p1 = h ? w5 : w7;
            unsigned e0 = (unsigned)__shfl_xor((int)p0, 32);
            unsigned e1 = (unsigned)__shfl_xor((int)p1, 32);
            union { unsigned u[4]; short8 v; } pf;
            pf.u[0] = h ? e0 : w4; pf.u[1] = h ? e1 : w5;
            pf.u[2] = h ? w6 : e0; pf.u[3] = h ? w7 : e1;
            O0 = mfma_bf16(vb0, pf.v, O0); O1 = mfma_bf16(vb1, pf.v, O1);
            O2 = mfma_bf16(vb2, pf.v, O2); O3 = mfma_bf16(vb3, pf.v, O3);
        }
        ah0 = an0; ah1 = an1;
    }

    if (ch == 0 && lane < 32) Lpart[mq * NN + n0 + ln] = l_run;
    size_t obase = (size_t)mq * ((size_t)CC * NN);
    OGW(0, O0) OGW(1, O1) OGW(2, O2) OGW(3, O3)
}

// K4: fixed-max parts => single weight W[n] = gamma / sum_q L_q[n]. grid 36x256.
__global__ __launch_bounds__(256) void stats(
    const float* __restrict__ Lpart, const float* __restrict__ gamma,
    float* __restrict__ W)
{
    int n = blockIdx.x * 256 + threadIdx.x;
    float L = Lpart[n] + Lpart[NN + n] + Lpart[2 * NN + n] + Lpart[3 * NN + n];
    W[n] = gamma[0] / L;
}

// K5: out[c][n] = (sum_q Opart_q[c][n]) * W[n] + x[c][n]
__global__ __launch_bounds__(256) void combine(
    const unsigned short* __restrict__ Opart, const float* __restrict__ W,
    const float* __restrict__ x, float* __restrict__ out)
{
    int i = blockIdx.x * 256 + threadIdx.x;   // float4 index
    int flat = i * 4;
    int n = flat % NN;                        // 4-aligned, NN%4==0 so no row cross
    floatx4 acc = *(const floatx4*)&x[flat];
    floatx4 w = *(const floatx4*)&W[n];
    float s0 = 0.f, s1 = 0.f, s2 = 0.f, s3 = 0.f;
#pragma unroll
    for (int q = 0; q < 4; ++q) {
        ushortx4 o = *(const ushortx4*)(Opart + (size_t)q * ((size_t)CC * NN) + flat);
        s0 += bf2f(o[0]); s1 += bf2f(o[1]); s2 += bf2f(o[2]); s3 += bf2f(o[3]);
    }
    acc[0] += s0 * w[0]; acc[1] += s1 * w[1]; acc[2] += s2 * w[2]; acc[3] += s3 * w[3];
    *(floatx4*)&out[flat] = acc;
}

extern "C" void kernel_launch(void* const* d_in, const int* in_sizes, int n_in,
                              void* d_out, int out_size, void* d_ws, size_t ws_size,
                              hipStream_t stream) {
    const float* x  = (const float*)d_in[0];
    const float* xe = (const float*)d_in[1];
    const float* qw = (const float*)d_in[2];
    const float* qb = (const float*)d_in[3];
    const float* kw = (const float*)d_in[4];
    const float* kb = (const float*)d_in[5];
    const float* vw = (const float*)d_in[6];
    const float* vb = (const float*)d_in[7];
    const float* hp = (const float*)d_in[8];
    const float* wp = (const float*)d_in[9];
    const float* gm = (const float*)d_in[10];

    char* ws = (char*)d_ws;
    short* Qhi  = (short*)(ws + 0);                 // 589824 B
    short* Qlo  = (short*)(ws + 589824);            // 589824 B
    short* KP2  = (short*)(ws + 1179648);           // 589824 B
    short* WAhi = (short*)(ws + 1769472);           // 163840 B
    short* WAlo = (short*)(ws + 1933312);           // 163840 B
    short* VF   = (short*)(ws + 2097152);           // 4718592 B, ends 6815744
    unsigned short* Opart = (unsigned short*)(ws + 6815744);   // 18874368 B, ends 25690112
    // XB/EB staging overlays Opart (consumed by gemm_all before flash writes Opart)
    short* XBhi = (short*)(ws + 6815744);           // 4718592 B each
    short* XBlo = (short*)(ws + 11534336);
    short* EBhi = (short*)(ws + 16252928);
    short* EBlo = (short*)(ws + 20971520);
    float* Lpart = (float*)(ws + 25837568);         // 147456 B
    float* W     = (float*)(ws + 25985024);         // 36864 B used

    prep<<<dim3(1152, 2), dim3(256), 0, stream>>>(x, xe, XBhi, XBlo, EBhi, EBlo);
    wprep<<<dim3(40), dim3(256), 0, stream>>>(qw, kw, vw, WAhi, WAlo);
    gemm_all<<<dim3(144, 5), dim3(256), 0, stream>>>(
        XBhi, XBlo, EBhi, EBlo, WAhi, WAlo, qb, kb, hp, wp, vb, Qhi, Qlo, KP2, VF);
    flash<<<dim3(1152), dim3(128), 0, stream>>>(Qhi, Qlo, KP2, VF, Opart, Lpart);
    stats<<<dim3(36), dim3(256), 0, stream>>>(Lpart, gm, W);
    combine<<<dim3(2304), dim3(256), 0, stream>>>(Opart, W, x, (float*)d_out);
}